// Round 17
// baseline (535.917 us; speedup 1.0000x reference)
//
#include <hip/hip_runtime.h>
#include <math.h>

#define NN 50000
#define RR 8
#define EE 800000
#define RN 400000            // RR * NN
#define DIN 128
#define K1 1024              // RR * DIN
#define KTOT 1152            // K1 + DIN
#define NBLK 391             // ceil(RN / 1024)
#define LDW 1160             // LDS row width (elems) = 145 16B-chunks (ODD -> natural
                             // per-row bank rotation; NO XOR swizzle — R10 post-mortem)

// ---------------- workspace layout (bytes) ----------------
#define OFF_HB0  0UL           // h bf16: [NN][128] = 12,800,000
#define OFF_HB1  12800000UL    // h bf16: [NN][128] = 12,800,000
#define OFF_XB   25600000UL    // x bf16: [NN][128] = 12,800,000
#define OFF_LG   38400000UL    // logits f32: [NN][64] = 12,800,000
#define OFF_WT   51200000UL    // W^T bf16: 4 x 147456 elems = 1,179,648
#define OFF_OFFS 52379648UL    // offsets: (RN+1) ints -> 1,600,128
#define OFF_CUR  53979776UL    // hist: RN ints = 1,600,000
#define OFF_SRT  55579776UL    // sorted_src: EE ints = 3,200,000
#define OFF_BS   58779776UL    // block sums = 4,096
#define WS_NEED  58783872UL

typedef short bf16x8 __attribute__((ext_vector_type(8)));
typedef float f32x4 __attribute__((ext_vector_type(4)));

__device__ __forceinline__ unsigned f2bf(float f) {       // RNE f32 -> bf16 bits
    unsigned x = __float_as_uint(f);
    return (x + 0x7fffu + ((x >> 16) & 1u)) >> 16;
}
__device__ __forceinline__ float bflo(unsigned p) { return __uint_as_float(p << 16); }
__device__ __forceinline__ float bfhi(unsigned p) { return __uint_as_float(p & 0xffff0000u); }

// ---------------- one-time converts ----------------
__global__ void k_cvt(const float* __restrict__ x, ushort* __restrict__ xb) {
    int i = blockIdx.x * 256 + threadIdx.x;
    if (i >= NN * 32) return;                 // float4 granules
    float4 v = ((const float4*)x)[i];
    ushort4 o;
    o.x = (ushort)f2bf(v.x); o.y = (ushort)f2bf(v.y);
    o.z = (ushort)f2bf(v.z); o.w = (ushort)f2bf(v.w);
    ((ushort4*)xb)[i] = o;
}

// build W^T[o][k] bf16, k in [0,1152): k<1024 -> W[k>>7][k&127][o], else root[k-1024][o]
__global__ void k_wt(const float* __restrict__ W, const float* __restrict__ Rt,
                     ushort* __restrict__ WT, int O) {
    int o = blockIdx.x;
    for (int k = threadIdx.x; k < KTOT; k += 256) {
        float v = (k < K1)
            ? W[(size_t)(k >> 7) * 128 * O + (size_t)(k & 127) * O + o]
            : Rt[(size_t)(k - K1) * O + o];
        WT[(size_t)o * KTOT + k] = (ushort)f2bf(v);
    }
}

// ---------------- edge preprocessing (counting sort by s = dst*8 + r) ----------------
__global__ void k_hist(const int* __restrict__ ei, const int* __restrict__ et,
                       int* __restrict__ hist) {
    int e = blockIdx.x * blockDim.x + threadIdx.x;
    if (e >= EE) return;
    atomicAdd(&hist[ei[EE + e] * RR + et[e]], 1);
}

__global__ void k_scan1(const int* __restrict__ hist, int* __restrict__ offs,
                        int* __restrict__ bsums) {
    __shared__ int tmp[1024];
    int tid = threadIdx.x;
    int g = blockIdx.x * 1024 + tid;
    int v = (g < RN) ? hist[g] : 0;
    tmp[tid] = v;
    __syncthreads();
    for (int off = 1; off < 1024; off <<= 1) {
        int t = tmp[tid];
        if (tid >= off) t += tmp[tid - off];
        __syncthreads();
        tmp[tid] = t;
        __syncthreads();
    }
    if (g < RN) offs[g] = tmp[tid] - v;
    if (tid == 1023) bsums[blockIdx.x] = tmp[1023];
}

__global__ void k_scan2(int* __restrict__ bsums) {
    __shared__ int tmp[1024];
    int tid = threadIdx.x;
    int v = (tid < NBLK) ? bsums[tid] : 0;
    tmp[tid] = v;
    __syncthreads();
    for (int off = 1; off < 1024; off <<= 1) {
        int t = tmp[tid];
        if (tid >= off) t += tmp[tid - off];
        __syncthreads();
        tmp[tid] = t;
        __syncthreads();
    }
    if (tid < NBLK) bsums[tid] = tmp[tid] - v;
}

__global__ void k_scan3(int* __restrict__ offs, const int* __restrict__ bsums) {
    int g = blockIdx.x * 1024 + threadIdx.x;
    if (g < RN) offs[g] += bsums[blockIdx.x];
}

// DESTRUCTIVE scatter (R17): atomicAdd on offs itself. Post-condition:
// offs[s] = original offs[s+1] (index shift by -1) — consumers read
// beg(s) = s? offs[s-1] : 0, end(s) = offs[s]. Saves cur[] + one memset.
__global__ void k_scatter(const int* __restrict__ ei, const int* __restrict__ et,
                          int* __restrict__ offs, int* __restrict__ ssrc) {
    int e = blockIdx.x * blockDim.x + threadIdx.x;
    if (e >= EE) return;
    int s = ei[EE + e] * RR + et[e];
    ssrc[atomicAdd(&offs[s], 1)] = ei[e];
}

// ---------------- fused layer: agg -> LDS -> MFMA, one barrier ----------------
// R17 = R16 (champion: 32-node block, 512 thr, A/B chain interleave, 4-deep
// unroll) + DYNAMIC NODE QUEUE: per-wave static 4-node assignment made the
// barrier wait on the slowest wave (~+35% tail, Poisson(16) degree). Waves now
// grab node-pairs from an LDS counter (16 grabs of 2; 32 even -> no tail dup).
// Boundary reads use the shifted (destructive-scatter) offs convention.
template<int O, bool RELU, bool OUTF32>
__global__ __launch_bounds__(512) void k_fused(
        const ushort* __restrict__ hb, const int* __restrict__ offs,
        const int* __restrict__ ssrc, const ushort* __restrict__ WT,
        const float* __restrict__ bias, void* __restrict__ outv) {
    __shared__ ushort As[32 * LDW];
    __shared__ int qctr;
    const int tid = threadIdx.x;
    const int lane = tid & 63;
    const int w = tid >> 6;                  // 0..7
    const int q = lane >> 4;                 // quarter 0..3 = relation slot
    const int ll = lane & 15;                // 16B chunk within row
    const int nbase = blockIdx.x * 32;
    const uint4* h16 = (const uint4*)hb;     // h row = 16 uint4

    // ---- root rows first (independent loads issue early): chunks [128,144)
    {
        int row = tid >> 4;                  // 0..31
        int cc = tid & 15;
        uint4 v = h16[(size_t)min(nbase + row, NN - 1) * 16 + cc];
        *(uint4*)(&As[row * LDW + (128 + cc) * 8]) = v;
    }
    if (tid == 0) qctr = 0;
    __syncthreads();                         // qctr visible to all waves

    // ---- phase 1: dynamic pair-grab; A/B chains interleaved
    for (;;) {
        int base;
        if (lane == 0) base = atomicAdd(&qctr, 2);
        base = __shfl(base, 0);              // full-exec broadcast
        if (base >= 32) break;               // wave-uniform exit
        int nlA = base, nlB = base + 1;
        int nA = min(nbase + nlA, NN - 1);   // clamp tail (junk masked later)
        int nB = min(nbase + nlB, NN - 1);
        // one offs load: lanes 0-31 node A bounds, 32-63 node B bounds.
        // shifted convention: bound k of node n = offs[n*8+k-1] (0 if idx<0)
        int idx = ((lane < 32) ? nA : nB) * 8 + min(lane & 31, 8) - 1;
        int b = (idx >= 0) ? offs[idx] : 0;
        int b0A = __shfl(b, 0),  b8A = __shfl(b, 8);
        int b0B = __shfl(b, 32), b8B = __shfl(b, 40);
        int nbA = b8A - b0A, nbB = b8B - b0B;
        int svA = ssrc[min(b0A + min(lane, max(nbA - 1, 0)), EE - 1)];
        int svB = ssrc[min(b0B + min(lane, max(nbB - 1, 0)), EE - 1)];
#pragma unroll
        for (int p = 0; p < 2; ++p) {        // relation pass: r = p*4 + q
            int r = p * 4 + q;
            int begA = __shfl(b, r),      endA = __shfl(b, r + 1);
            int begB = __shfl(b, 32 + r), endB = __shfl(b, 32 + r + 1);
            int lenA = endA - begA, lenB = endB - begB;
            int mxA = max(max(__shfl(lenA, 0), __shfl(lenA, 16)),
                          max(__shfl(lenA, 32), __shfl(lenA, 48)));
            int mxB = max(max(__shfl(lenB, 0), __shfl(lenB, 16)),
                          max(__shfl(lenB, 32), __shfl(lenB, 48)));
            int mx = max(mxA, mxB);          // wave-uniform trip count
            int beglA = begA - b0A, beglB = begB - b0B;
            float aA0 = 0.f, aA1 = 0.f, aA2 = 0.f, aA3 = 0.f;
            float aA4 = 0.f, aA5 = 0.f, aA6 = 0.f, aA7 = 0.f;
            float aB0 = 0.f, aB1 = 0.f, aB2 = 0.f, aB3 = 0.f;
            float aB4 = 0.f, aB5 = 0.f, aB6 = 0.f, aB7 = 0.f;
            for (int j = 0; j < mx; j += 4) {   // uniform trip: full exec
                int eA = beglA + j, eB = beglB + j;
                int sA0 = __shfl(svA, min(eA, 63));       // shfl ALWAYS full exec
                int sA1 = __shfl(svA, min(eA + 1, 63));
                int sA2 = __shfl(svA, min(eA + 2, 63));
                int sA3 = __shfl(svA, min(eA + 3, 63));
                int sB0 = __shfl(svB, min(eB, 63));
                int sB1 = __shfl(svB, min(eB + 1, 63));
                int sB2 = __shfl(svB, min(eB + 2, 63));
                int sB3 = __shfl(svB, min(eB + 3, 63));
                if (eA + 3 >= 64) {              // rare: degree > 64
                    sA0 = ssrc[min(b0A + eA, EE - 1)];
                    sA1 = ssrc[min(b0A + eA + 1, EE - 1)];
                    sA2 = ssrc[min(b0A + eA + 2, EE - 1)];
                    sA3 = ssrc[min(b0A + eA + 3, EE - 1)];
                }
                if (eB + 3 >= 64) {
                    sB0 = ssrc[min(b0B + eB, EE - 1)];
                    sB1 = ssrc[min(b0B + eB + 1, EE - 1)];
                    sB2 = ssrc[min(b0B + eB + 2, EE - 1)];
                    sB3 = ssrc[min(b0B + eB + 3, EE - 1)];
                }
                uint4 uA0 = h16[(size_t)sA0 * 16 + ll];   // 8 loads in flight
                uint4 uA1 = h16[(size_t)sA1 * 16 + ll];
                uint4 uA2 = h16[(size_t)sA2 * 16 + ll];
                uint4 uA3 = h16[(size_t)sA3 * 16 + ll];
                uint4 uB0 = h16[(size_t)sB0 * 16 + ll];
                uint4 uB1 = h16[(size_t)sB1 * 16 + ll];
                uint4 uB2 = h16[(size_t)sB2 * 16 + ll];
                uint4 uB3 = h16[(size_t)sB3 * 16 + ll];
                if (j < lenA) {
                    aA0 += bflo(uA0.x); aA1 += bfhi(uA0.x);
                    aA2 += bflo(uA0.y); aA3 += bfhi(uA0.y);
                    aA4 += bflo(uA0.z); aA5 += bfhi(uA0.z);
                    aA6 += bflo(uA0.w); aA7 += bfhi(uA0.w);
                }
                if (j + 1 < lenA) {
                    aA0 += bflo(uA1.x); aA1 += bfhi(uA1.x);
                    aA2 += bflo(uA1.y); aA3 += bfhi(uA1.y);
                    aA4 += bflo(uA1.z); aA5 += bfhi(uA1.z);
                    aA6 += bflo(uA1.w); aA7 += bfhi(uA1.w);
                }
                if (j + 2 < lenA) {
                    aA0 += bflo(uA2.x); aA1 += bfhi(uA2.x);
                    aA2 += bflo(uA2.y); aA3 += bfhi(uA2.y);
                    aA4 += bflo(uA2.z); aA5 += bfhi(uA2.z);
                    aA6 += bflo(uA2.w); aA7 += bfhi(uA2.w);
                }
                if (j + 3 < lenA) {
                    aA0 += bflo(uA3.x); aA1 += bfhi(uA3.x);
                    aA2 += bflo(uA3.y); aA3 += bfhi(uA3.y);
                    aA4 += bflo(uA3.z); aA5 += bfhi(uA3.z);
                    aA6 += bflo(uA3.w); aA7 += bfhi(uA3.w);
                }
                if (j < lenB) {
                    aB0 += bflo(uB0.x); aB1 += bfhi(uB0.x);
                    aB2 += bflo(uB0.y); aB3 += bfhi(uB0.y);
                    aB4 += bflo(uB0.z); aB5 += bfhi(uB0.z);
                    aB6 += bflo(uB0.w); aB7 += bfhi(uB0.w);
                }
                if (j + 1 < lenB) {
                    aB0 += bflo(uB1.x); aB1 += bfhi(uB1.x);
                    aB2 += bflo(uB1.y); aB3 += bfhi(uB1.y);
                    aB4 += bflo(uB1.z); aB5 += bfhi(uB1.z);
                    aB6 += bflo(uB1.w); aB7 += bfhi(uB1.w);
                }
                if (j + 2 < lenB) {
                    aB0 += bflo(uB2.x); aB1 += bfhi(uB2.x);
                    aB2 += bflo(uB2.y); aB3 += bfhi(uB2.y);
                    aB4 += bflo(uB2.z); aB5 += bfhi(uB2.z);
                    aB6 += bflo(uB2.w); aB7 += bfhi(uB2.w);
                }
                if (j + 3 < lenB) {
                    aB0 += bflo(uB3.x); aB1 += bfhi(uB3.x);
                    aB2 += bflo(uB3.y); aB3 += bfhi(uB3.y);
                    aB4 += bflo(uB3.z); aB5 += bfhi(uB3.z);
                    aB6 += bflo(uB3.w); aB7 += bfhi(uB3.w);
                }
            }
            float invA = 1.0f / (float)max(lenA, 1);
            float invB = 1.0f / (float)max(lenB, 1);
            uint4 oA, oB;
            oA.x = f2bf(aA0 * invA) | (f2bf(aA1 * invA) << 16);
            oA.y = f2bf(aA2 * invA) | (f2bf(aA3 * invA) << 16);
            oA.z = f2bf(aA4 * invA) | (f2bf(aA5 * invA) << 16);
            oA.w = f2bf(aA6 * invA) | (f2bf(aA7 * invA) << 16);
            oB.x = f2bf(aB0 * invB) | (f2bf(aB1 * invB) << 16);
            oB.y = f2bf(aB2 * invB) | (f2bf(aB3 * invB) << 16);
            oB.z = f2bf(aB4 * invB) | (f2bf(aB5 * invB) << 16);
            oB.w = f2bf(aB6 * invB) | (f2bf(aB7 * invB) << 16);
            *(uint4*)(&As[nlA * LDW + (r * 16 + ll) * 8]) = oA;
            *(uint4*)(&As[nlB * LDW + (r * 16 + ll) * 8]) = oB;
        }
    }
    __syncthreads();
    // ---- phase 2: MFMA. O=128 -> wave w: col-tile w, m-subtiles 0,1;
    //      O=64 -> wave w: col-tile w&3, m-subtile w>>2.
    constexpr int NTILE = O / 16;
    const int cw = w % NTILE;
    const int mt0 = (NTILE == 8) ? 0 : (w / NTILE);
    constexpr int NMT = (NTILE == 8) ? 2 : 1;
    const int lr = lane & 15, hi = lane >> 4;
    f32x4 acc[NMT] = {};
    const ushort* wcol = WT + (size_t)(cw * 16 + lr) * KTOT + hi * 8;
#pragma unroll
    for (int ks = 0; ks < 36; ++ks) {
        bf16x8 bb = *(const bf16x8*)(wcol + ks * 32);
        int g = ks * 4 + hi;
#pragma unroll
        for (int m = 0; m < NMT; ++m) {
            int row = (mt0 + m) * 16 + lr;
            bf16x8 a = *(const bf16x8*)(&As[row * LDW + g * 8]);
            acc[m] = __builtin_amdgcn_mfma_f32_16x16x32_bf16(a, bb, acc[m], 0, 0, 0);
        }
    }
    int col = cw * 16 + lr;
    float bs = bias[col];
#pragma unroll
    for (int m = 0; m < NMT; ++m) {
#pragma unroll
        for (int j = 0; j < 4; ++j) {        // C/D: col=lane&15, row=(lane>>4)*4+j
            int row = nbase + (mt0 + m) * 16 + hi * 4 + j;
            if (row >= NN) continue;
            float v = acc[m][j] + bs;
            if (RELU) v = fmaxf(v, 0.f);
            if (OUTF32) ((float*)outv)[(size_t)row * O + col] = v;
            else ((ushort*)outv)[(size_t)row * O + col] = (ushort)f2bf(v);
        }
    }
}

// ---------------- final log_softmax over 64 cols ----------------
__global__ void k_logsoftmax(const float* __restrict__ in, float* __restrict__ out) {
    int row = blockIdx.x * 4 + (threadIdx.x >> 6);
    int lane = threadIdx.x & 63;
    if (row >= NN) return;
    float v = in[(size_t)row * 64 + lane];
    float m = v;
#pragma unroll
    for (int off = 32; off; off >>= 1) m = fmaxf(m, __shfl_xor(m, off, 64));
    float e = expf(v - m);
    float s = e;
#pragma unroll
    for (int off = 32; off; off >>= 1) s += __shfl_xor(s, off, 64);
    out[(size_t)row * 64 + lane] = v - m - logf(s);
}

extern "C" void kernel_launch(void* const* d_in, const int* in_sizes, int n_in,
                              void* d_out, int out_size, void* d_ws, size_t ws_size,
                              hipStream_t stream) {
    const float* x  = (const float*)d_in[0];
    const int*   ei = (const int*)d_in[1];
    const int*   et = (const int*)d_in[2];
    const float* W[4]    = {(const float*)d_in[3], (const float*)d_in[6],
                            (const float*)d_in[9], (const float*)d_in[12]};
    const float* root[4] = {(const float*)d_in[4], (const float*)d_in[7],
                            (const float*)d_in[10], (const float*)d_in[13]};
    const float* bias[4] = {(const float*)d_in[5], (const float*)d_in[8],
                            (const float*)d_in[11], (const float*)d_in[14]};

    if (ws_size < WS_NEED) return;

    char* ws = (char*)d_ws;
    ushort* hb0  = (ushort*)(ws + OFF_HB0);
    ushort* hb1  = (ushort*)(ws + OFF_HB1);
    ushort* xb   = (ushort*)(ws + OFF_XB);
    float*  lg   = (float*)(ws + OFF_LG);
    ushort* WT   = (ushort*)(ws + OFF_WT);
    int*   offs  = (int*)(ws + OFF_OFFS);
    int*   hist  = (int*)(ws + OFF_CUR);
    int*   ssrc  = (int*)(ws + OFF_SRT);
    int*   bsums = (int*)(ws + OFF_BS);
    ushort* WTl[4] = {WT, WT + 147456, WT + 2 * 147456, WT + 3 * 147456};

    // one-time converts
    k_cvt<<<(NN * 32 + 255) / 256, 256, 0, stream>>>(x, xb);
    k_wt<<<128, 256, 0, stream>>>(W[0], root[0], WTl[0], 128);
    k_wt<<<128, 256, 0, stream>>>(W[1], root[1], WTl[1], 128);
    k_wt<<<128, 256, 0, stream>>>(W[2], root[2], WTl[2], 128);
    k_wt<<<64,  256, 0, stream>>>(W[3], root[3], WTl[3], 64);

    // edge sort by segment key s = dst*8 + etype (destructive-offs variant)
    hipMemsetAsync(hist, 0, RN * sizeof(int), stream);
    k_hist<<<(EE + 255) / 256, 256, 0, stream>>>(ei, et, hist);
    k_scan1<<<NBLK, 1024, 0, stream>>>(hist, offs, bsums);
    k_scan2<<<1, 1024, 0, stream>>>(bsums);
    k_scan3<<<NBLK, 1024, 0, stream>>>(offs, bsums);
    k_scatter<<<(EE + 255) / 256, 256, 0, stream>>>(ei, et, offs, ssrc);

    const int G = (NN + 31) / 32;   // 1563
    k_fused<128, true,  false><<<G, 512, 0, stream>>>(xb,  offs, ssrc, WTl[0], bias[0], hb0);
    k_fused<128, true,  false><<<G, 512, 0, stream>>>(hb0, offs, ssrc, WTl[1], bias[1], hb1);
    k_fused<128, true,  false><<<G, 512, 0, stream>>>(hb1, offs, ssrc, WTl[2], bias[2], hb0);
    k_fused<64,  false, true ><<<G, 512, 0, stream>>>(hb0, offs, ssrc, WTl[3], bias[3], lg);
    k_logsoftmax<<<(NN + 3) / 4, 256, 0, stream>>>(lg, (float*)d_out);
}

// Round 18
// 528.354 us; speedup vs baseline: 1.0143x; 1.0143x over previous
//
#include <hip/hip_runtime.h>
#include <math.h>

#define NN 50000
#define RR 8
#define EE 800000
#define RN 400000            // RR * NN
#define DIN 128
#define K1 1024              // RR * DIN
#define KTOT 1152            // K1 + DIN
#define NBLK 391             // ceil(RN / 1024)
#define LDW 1160             // LDS row width (elems) = 145 16B-chunks (ODD -> natural
                             // per-row bank rotation; NO XOR swizzle — R10 post-mortem)
#define ECAP 2048            // block-local edge cache (ushort); mean 512, sd 23

// ---------------- workspace layout (bytes) ----------------
#define OFF_HB0  0UL           // h bf16: [NN][128] = 12,800,000
#define OFF_HB1  12800000UL    // h bf16: [NN][128] = 12,800,000
#define OFF_XB   25600000UL    // x bf16: [NN][128] = 12,800,000
#define OFF_LG   38400000UL    // logits f32: [NN][64] = 12,800,000
#define OFF_WT   51200000UL    // W^T bf16: 4 x 147456 elems = 1,179,648
#define OFF_OFFS 52379648UL    // offsets: (RN+1) ints -> 1,600,128
#define OFF_CUR  53979776UL    // cursor/hist: RN ints = 1,600,000
#define OFF_SRT  55579776UL    // sorted_src: EE ints = 3,200,000
#define OFF_BS   58779776UL    // block sums = 4,096
#define WS_NEED  58783872UL

typedef short bf16x8 __attribute__((ext_vector_type(8)));
typedef float f32x4 __attribute__((ext_vector_type(4)));

__device__ __forceinline__ unsigned f2bf(float f) {       // RNE f32 -> bf16 bits
    unsigned x = __float_as_uint(f);
    return (x + 0x7fffu + ((x >> 16) & 1u)) >> 16;
}
__device__ __forceinline__ float bflo(unsigned p) { return __uint_as_float(p << 16); }
__device__ __forceinline__ float bfhi(unsigned p) { return __uint_as_float(p & 0xffff0000u); }

// ---------------- one-time converts ----------------
__global__ void k_cvt(const float* __restrict__ x, ushort* __restrict__ xb) {
    int i = blockIdx.x * 256 + threadIdx.x;
    if (i >= NN * 32) return;                 // float4 granules
    float4 v = ((const float4*)x)[i];
    ushort4 o;
    o.x = (ushort)f2bf(v.x); o.y = (ushort)f2bf(v.y);
    o.z = (ushort)f2bf(v.z); o.w = (ushort)f2bf(v.w);
    ((ushort4*)xb)[i] = o;
}

// build W^T[o][k] bf16, k in [0,1152): k<1024 -> W[k>>7][k&127][o], else root[k-1024][o]
__global__ void k_wt(const float* __restrict__ W, const float* __restrict__ Rt,
                     ushort* __restrict__ WT, int O) {
    int o = blockIdx.x;
    for (int k = threadIdx.x; k < KTOT; k += 256) {
        float v = (k < K1)
            ? W[(size_t)(k >> 7) * 128 * O + (size_t)(k & 127) * O + o]
            : Rt[(size_t)(k - K1) * O + o];
        WT[(size_t)o * KTOT + k] = (ushort)f2bf(v);
    }
}

// ---------------- edge preprocessing (counting sort by s = dst*8 + r) ----------------
__global__ void k_hist(const int* __restrict__ ei, const int* __restrict__ et,
                       int* __restrict__ hist) {
    int e = blockIdx.x * blockDim.x + threadIdx.x;
    if (e >= EE) return;
    atomicAdd(&hist[ei[EE + e] * RR + et[e]], 1);
}

__global__ void k_scan1(const int* __restrict__ hist, int* __restrict__ offs,
                        int* __restrict__ bsums) {
    __shared__ int tmp[1024];
    int tid = threadIdx.x;
    int g = blockIdx.x * 1024 + tid;
    int v = (g < RN) ? hist[g] : 0;
    tmp[tid] = v;
    __syncthreads();
    for (int off = 1; off < 1024; off <<= 1) {
        int t = tmp[tid];
        if (tid >= off) t += tmp[tid - off];
        __syncthreads();
        tmp[tid] = t;
        __syncthreads();
    }
    if (g < RN) offs[g] = tmp[tid] - v;
    if (tid == 1023) bsums[blockIdx.x] = tmp[1023];
}

__global__ void k_scan2(int* __restrict__ bsums) {
    __shared__ int tmp[1024];
    int tid = threadIdx.x;
    int v = (tid < NBLK) ? bsums[tid] : 0;
    tmp[tid] = v;
    __syncthreads();
    for (int off = 1; off < 1024; off <<= 1) {
        int t = tmp[tid];
        if (tid >= off) t += tmp[tid - off];
        __syncthreads();
        tmp[tid] = t;
        __syncthreads();
    }
    if (tid < NBLK) bsums[tid] = tmp[tid] - v;
}

__global__ void k_scan3(int* __restrict__ offs, const int* __restrict__ bsums) {
    int g = blockIdx.x * 1024 + threadIdx.x;
    if (g < RN) offs[g] += bsums[blockIdx.x];
    else if (g == RN) offs[RN] = EE;
}

__global__ void k_scatter(const int* __restrict__ ei, const int* __restrict__ et,
                          const int* __restrict__ offs, int* __restrict__ cur,
                          int* __restrict__ ssrc) {
    int e = blockIdx.x * blockDim.x + threadIdx.x;
    if (e >= EE) return;
    int s = ei[EE + e] * RR + et[e];
    ssrc[offs[s] + atomicAdd(&cur[s], 1)] = ei[e];
}

// ---------------- fused layer: agg -> LDS -> MFMA ----------------
// R18 = R16 (champion) with the ssrc broadcast machinery replaced by a
// BLOCK-LOCAL LDS EDGE CACHE: a block's 32 nodes own a contiguous ssrc slice
// (mean 512 edges, sd 23; ECAP=2048 w/ global fallback). Loaded once,
// coalesced, as ushort (node ids < 65536) + 257 boundaries. Consequences:
// (1) ZERO __shfl in the gather phase (srcs via broadcast ds_read);
// (2) trip counts quarter-local — mx = max(lenA,lenB), no wave-wide max, ~2x
//     fewer garbage gathers WITHOUT guarding loads (R13 lesson);
// (3) per-node sv setup loads gone. A/B interleave + 4-deep unroll kept
//     (8 gathers in flight). LDS 79.4KB -> still 2 blocks/CU.
template<int O, bool RELU, bool OUTF32>
__global__ __launch_bounds__(512) void k_fused(
        const ushort* __restrict__ hb, const int* __restrict__ offs,
        const int* __restrict__ ssrc, const ushort* __restrict__ WT,
        const float* __restrict__ bias, void* __restrict__ outv) {
    __shared__ ushort As[32 * LDW];
    __shared__ int sOffs[257];
    __shared__ ushort sEdge[ECAP];
    const int tid = threadIdx.x;
    const int lane = tid & 63;
    const int w = tid >> 6;                  // 0..7
    const int q = lane >> 4;                 // quarter 0..3 = relation slot
    const int ll = lane & 15;                // 16B chunk within row
    const int nbase = blockIdx.x * 32;
    const int obase = nbase * 8;
    const uint4* h16 = (const uint4*)hb;     // h row = 16 uint4

    // ---- phase 0: boundaries + edge cache + root rows (all coalesced)
    const int eb0 = offs[obase];
    const int ebN = offs[min(obase + 256, RN)];
    const int nE = min(ebN - eb0, ECAP);
    if (tid < 257) sOffs[tid] = offs[min(obase + tid, RN)];
    for (int e = tid; e < nE; e += 512) sEdge[e] = (ushort)ssrc[eb0 + e];
    {
        int row = tid >> 4;                  // 0..31
        int cc = tid & 15;
        uint4 v = h16[(size_t)min(nbase + row, NN - 1) * 16 + cc];
        *(uint4*)(&As[row * LDW + (128 + cc) * 8]) = v;
    }
    __syncthreads();

    // src fetch: LDS for local idx < ECAP, global fallback (degenerate blocks)
    auto esrc = [&](int le) -> int {
        return (le < ECAP) ? (int)sEdge[le] : ssrc[min(eb0 + le, EE - 1)];
    };

    // ---- phase 1: 2 node-pairs per wave, A/B chains interleaved, no shfl
    for (int i = 0; i < 2; ++i) {            // wave-uniform
        int nlA = w * 4 + i * 2;
        int nlB = nlA + 1;
#pragma unroll
        for (int p = 0; p < 2; ++p) {        // relation pass: r = p*4 + q
            int r = p * 4 + q;
            int begA = sOffs[nlA * 8 + r] - eb0;
            int endA = sOffs[nlA * 8 + r + 1] - eb0;
            int begB = sOffs[nlB * 8 + r] - eb0;
            int endB = sOffs[nlB * 8 + r + 1] - eb0;
            int lenA = endA - begA, lenB = endB - begB;
            int mx = max(lenA, lenB);        // quarter-local trip count
            int cA = max(endA - 1, 0), cB = max(endB - 1, 0);
            float aA0 = 0.f, aA1 = 0.f, aA2 = 0.f, aA3 = 0.f;
            float aA4 = 0.f, aA5 = 0.f, aA6 = 0.f, aA7 = 0.f;
            float aB0 = 0.f, aB1 = 0.f, aB2 = 0.f, aB3 = 0.f;
            float aB4 = 0.f, aB5 = 0.f, aB6 = 0.f, aB7 = 0.f;
            for (int j = 0; j < mx; j += 4) {
                int sA0 = esrc(min(begA + j,     cA));   // clamped idx, loads
                int sA1 = esrc(min(begA + j + 1, cA));   // unconditional
                int sA2 = esrc(min(begA + j + 2, cA));
                int sA3 = esrc(min(begA + j + 3, cA));
                int sB0 = esrc(min(begB + j,     cB));
                int sB1 = esrc(min(begB + j + 1, cB));
                int sB2 = esrc(min(begB + j + 2, cB));
                int sB3 = esrc(min(begB + j + 3, cB));
                uint4 uA0 = h16[(size_t)sA0 * 16 + ll];  // 8 gathers in flight
                uint4 uA1 = h16[(size_t)sA1 * 16 + ll];
                uint4 uA2 = h16[(size_t)sA2 * 16 + ll];
                uint4 uA3 = h16[(size_t)sA3 * 16 + ll];
                uint4 uB0 = h16[(size_t)sB0 * 16 + ll];
                uint4 uB1 = h16[(size_t)sB1 * 16 + ll];
                uint4 uB2 = h16[(size_t)sB2 * 16 + ll];
                uint4 uB3 = h16[(size_t)sB3 * 16 + ll];
                if (j < lenA) {
                    aA0 += bflo(uA0.x); aA1 += bfhi(uA0.x);
                    aA2 += bflo(uA0.y); aA3 += bfhi(uA0.y);
                    aA4 += bflo(uA0.z); aA5 += bfhi(uA0.z);
                    aA6 += bflo(uA0.w); aA7 += bfhi(uA0.w);
                }
                if (j + 1 < lenA) {
                    aA0 += bflo(uA1.x); aA1 += bfhi(uA1.x);
                    aA2 += bflo(uA1.y); aA3 += bfhi(uA1.y);
                    aA4 += bflo(uA1.z); aA5 += bfhi(uA1.z);
                    aA6 += bflo(uA1.w); aA7 += bfhi(uA1.w);
                }
                if (j + 2 < lenA) {
                    aA0 += bflo(uA2.x); aA1 += bfhi(uA2.x);
                    aA2 += bflo(uA2.y); aA3 += bfhi(uA2.y);
                    aA4 += bflo(uA2.z); aA5 += bfhi(uA2.z);
                    aA6 += bflo(uA2.w); aA7 += bfhi(uA2.w);
                }
                if (j + 3 < lenA) {
                    aA0 += bflo(uA3.x); aA1 += bfhi(uA3.x);
                    aA2 += bflo(uA3.y); aA3 += bfhi(uA3.y);
                    aA4 += bflo(uA3.z); aA5 += bfhi(uA3.z);
                    aA6 += bflo(uA3.w); aA7 += bfhi(uA3.w);
                }
                if (j < lenB) {
                    aB0 += bflo(uB0.x); aB1 += bfhi(uB0.x);
                    aB2 += bflo(uB0.y); aB3 += bfhi(uB0.y);
                    aB4 += bflo(uB0.z); aB5 += bfhi(uB0.z);
                    aB6 += bflo(uB0.w); aB7 += bfhi(uB0.w);
                }
                if (j + 1 < lenB) {
                    aB0 += bflo(uB1.x); aB1 += bfhi(uB1.x);
                    aB2 += bflo(uB1.y); aB3 += bfhi(uB1.y);
                    aB4 += bflo(uB1.z); aB5 += bfhi(uB1.z);
                    aB6 += bflo(uB1.w); aB7 += bfhi(uB1.w);
                }
                if (j + 2 < lenB) {
                    aB0 += bflo(uB2.x); aB1 += bfhi(uB2.x);
                    aB2 += bflo(uB2.y); aB3 += bfhi(uB2.y);
                    aB4 += bflo(uB2.z); aB5 += bfhi(uB2.z);
                    aB6 += bflo(uB2.w); aB7 += bfhi(uB2.w);
                }
                if (j + 3 < lenB) {
                    aB0 += bflo(uB3.x); aB1 += bfhi(uB3.x);
                    aB2 += bflo(uB3.y); aB3 += bfhi(uB3.y);
                    aB4 += bflo(uB3.z); aB5 += bfhi(uB3.z);
                    aB6 += bflo(uB3.w); aB7 += bfhi(uB3.w);
                }
            }
            float invA = 1.0f / (float)max(lenA, 1);
            float invB = 1.0f / (float)max(lenB, 1);
            uint4 oA, oB;
            oA.x = f2bf(aA0 * invA) | (f2bf(aA1 * invA) << 16);
            oA.y = f2bf(aA2 * invA) | (f2bf(aA3 * invA) << 16);
            oA.z = f2bf(aA4 * invA) | (f2bf(aA5 * invA) << 16);
            oA.w = f2bf(aA6 * invA) | (f2bf(aA7 * invA) << 16);
            oB.x = f2bf(aB0 * invB) | (f2bf(aB1 * invB) << 16);
            oB.y = f2bf(aB2 * invB) | (f2bf(aB3 * invB) << 16);
            oB.z = f2bf(aB4 * invB) | (f2bf(aB5 * invB) << 16);
            oB.w = f2bf(aB6 * invB) | (f2bf(aB7 * invB) << 16);
            *(uint4*)(&As[nlA * LDW + (r * 16 + ll) * 8]) = oA;
            *(uint4*)(&As[nlB * LDW + (r * 16 + ll) * 8]) = oB;
        }
    }
    __syncthreads();
    // ---- phase 2: MFMA. O=128 -> wave w: col-tile w, m-subtiles 0,1;
    //      O=64 -> wave w: col-tile w&3, m-subtile w>>2.
    constexpr int NTILE = O / 16;
    const int cw = w % NTILE;
    const int mt0 = (NTILE == 8) ? 0 : (w / NTILE);
    constexpr int NMT = (NTILE == 8) ? 2 : 1;
    const int lr = lane & 15, hi = lane >> 4;
    f32x4 acc[NMT] = {};
    const ushort* wcol = WT + (size_t)(cw * 16 + lr) * KTOT + hi * 8;
#pragma unroll
    for (int ks = 0; ks < 36; ++ks) {
        bf16x8 bb = *(const bf16x8*)(wcol + ks * 32);
        int g = ks * 4 + hi;
#pragma unroll
        for (int m = 0; m < NMT; ++m) {
            int row = (mt0 + m) * 16 + lr;
            bf16x8 a = *(const bf16x8*)(&As[row * LDW + g * 8]);
            acc[m] = __builtin_amdgcn_mfma_f32_16x16x32_bf16(a, bb, acc[m], 0, 0, 0);
        }
    }
    int col = cw * 16 + lr;
    float bs = bias[col];
#pragma unroll
    for (int m = 0; m < NMT; ++m) {
#pragma unroll
        for (int j = 0; j < 4; ++j) {        // C/D: col=lane&15, row=(lane>>4)*4+j
            int row = nbase + (mt0 + m) * 16 + hi * 4 + j;
            if (row >= NN) continue;
            float v = acc[m][j] + bs;
            if (RELU) v = fmaxf(v, 0.f);
            if (OUTF32) ((float*)outv)[(size_t)row * O + col] = v;
            else ((ushort*)outv)[(size_t)row * O + col] = (ushort)f2bf(v);
        }
    }
}

// ---------------- final log_softmax over 64 cols ----------------
__global__ void k_logsoftmax(const float* __restrict__ in, float* __restrict__ out) {
    int row = blockIdx.x * 4 + (threadIdx.x >> 6);
    int lane = threadIdx.x & 63;
    if (row >= NN) return;
    float v = in[(size_t)row * 64 + lane];
    float m = v;
#pragma unroll
    for (int off = 32; off; off >>= 1) m = fmaxf(m, __shfl_xor(m, off, 64));
    float e = expf(v - m);
    float s = e;
#pragma unroll
    for (int off = 32; off; off >>= 1) s += __shfl_xor(s, off, 64);
    out[(size_t)row * 64 + lane] = v - m - logf(s);
}

extern "C" void kernel_launch(void* const* d_in, const int* in_sizes, int n_in,
                              void* d_out, int out_size, void* d_ws, size_t ws_size,
                              hipStream_t stream) {
    const float* x  = (const float*)d_in[0];
    const int*   ei = (const int*)d_in[1];
    const int*   et = (const int*)d_in[2];
    const float* W[4]    = {(const float*)d_in[3], (const float*)d_in[6],
                            (const float*)d_in[9], (const float*)d_in[12]};
    const float* root[4] = {(const float*)d_in[4], (const float*)d_in[7],
                            (const float*)d_in[10], (const float*)d_in[13]};
    const float* bias[4] = {(const float*)d_in[5], (const float*)d_in[8],
                            (const float*)d_in[11], (const float*)d_in[14]};

    if (ws_size < WS_NEED) return;

    char* ws = (char*)d_ws;
    ushort* hb0  = (ushort*)(ws + OFF_HB0);
    ushort* hb1  = (ushort*)(ws + OFF_HB1);
    ushort* xb   = (ushort*)(ws + OFF_XB);
    float*  lg   = (float*)(ws + OFF_LG);
    ushort* WT   = (ushort*)(ws + OFF_WT);
    int*   offs  = (int*)(ws + OFF_OFFS);
    int*   cur   = (int*)(ws + OFF_CUR);
    int*   ssrc  = (int*)(ws + OFF_SRT);
    int*   bsums = (int*)(ws + OFF_BS);
    ushort* WTl[4] = {WT, WT + 147456, WT + 2 * 147456, WT + 3 * 147456};

    // one-time converts
    k_cvt<<<(NN * 32 + 255) / 256, 256, 0, stream>>>(x, xb);
    k_wt<<<128, 256, 0, stream>>>(W[0], root[0], WTl[0], 128);
    k_wt<<<128, 256, 0, stream>>>(W[1], root[1], WTl[1], 128);
    k_wt<<<128, 256, 0, stream>>>(W[2], root[2], WTl[2], 128);
    k_wt<<<64,  256, 0, stream>>>(W[3], root[3], WTl[3], 64);

    // edge sort by segment key s = dst*8 + etype
    hipMemsetAsync(cur, 0, RN * sizeof(int), stream);
    k_hist<<<(EE + 255) / 256, 256, 0, stream>>>(ei, et, cur);
    k_scan1<<<NBLK, 1024, 0, stream>>>(cur, offs, bsums);
    k_scan2<<<1, 1024, 0, stream>>>(bsums);
    k_scan3<<<NBLK + 1, 1024, 0, stream>>>(offs, bsums);
    hipMemsetAsync(cur, 0, RN * sizeof(int), stream);
    k_scatter<<<(EE + 255) / 256, 256, 0, stream>>>(ei, et, offs, cur, ssrc);

    const int G = (NN + 31) / 32;   // 1563
    k_fused<128, true,  false><<<G, 512, 0, stream>>>(xb,  offs, ssrc, WTl[0], bias[0], hb0);
    k_fused<128, true,  false><<<G, 512, 0, stream>>>(hb0, offs, ssrc, WTl[1], bias[1], hb1);
    k_fused<128, true,  false><<<G, 512, 0, stream>>>(hb1, offs, ssrc, WTl[2], bias[2], hb0);
    k_fused<64,  false, true ><<<G, 512, 0, stream>>>(hb0, offs, ssrc, WTl[3], bias[3], lg);
    k_logsoftmax<<<(NN + 3) / 4, 256, 0, stream>>>(lg, (float*)d_out);
}

// Round 19
// 515.849 us; speedup vs baseline: 1.0389x; 1.0242x over previous
//
#include <hip/hip_runtime.h>
#include <math.h>

#define NN 50000
#define RR 8
#define EE 800000
#define RN 400000            // RR * NN
#define DIN 128
#define K1 1024              // RR * DIN
#define KTOT 1152            // K1 + DIN
#define NBLK 391             // ceil(RN / 1024)
#define LDWH 648             // half-tile LDS row width (elems) = 81 16B-chunks
                             // (ODD -> natural per-row bank rotation, no XOR)

// ---------------- workspace layout (bytes) ----------------
#define OFF_HB0  0UL           // h bf16: [NN][128] = 12,800,000
#define OFF_HB1  12800000UL    // h bf16: [NN][128] = 12,800,000
#define OFF_XB   25600000UL    // x bf16: [NN][128] = 12,800,000
#define OFF_LG   38400000UL    // (spare)
#define OFF_WT   51200000UL    // W^T bf16: 4 x 147456 elems = 1,179,648
#define OFF_OFFS 52379648UL    // offsets: (RN+1) ints -> 1,600,128
#define OFF_CUR  53979776UL    // cursor/hist: RN ints = 1,600,000
#define OFF_SRT  55579776UL    // sorted_src: EE ints = 3,200,000
#define OFF_BS   58779776UL    // block sums = 4,096
#define WS_NEED  58783872UL

typedef short bf16x8 __attribute__((ext_vector_type(8)));
typedef float f32x4 __attribute__((ext_vector_type(4)));

__device__ __forceinline__ unsigned f2bf(float f) {       // RNE f32 -> bf16 bits
    unsigned x = __float_as_uint(f);
    return (x + 0x7fffu + ((x >> 16) & 1u)) >> 16;
}
__device__ __forceinline__ float bflo(unsigned p) { return __uint_as_float(p << 16); }
__device__ __forceinline__ float bfhi(unsigned p) { return __uint_as_float(p & 0xffff0000u); }

// ---------------- one-time converts ----------------
__global__ void k_cvt(const float* __restrict__ x, ushort* __restrict__ xb) {
    int i = blockIdx.x * 256 + threadIdx.x;
    if (i >= NN * 32) return;                 // float4 granules
    float4 v = ((const float4*)x)[i];
    ushort4 o;
    o.x = (ushort)f2bf(v.x); o.y = (ushort)f2bf(v.y);
    o.z = (ushort)f2bf(v.z); o.w = (ushort)f2bf(v.w);
    ((ushort4*)xb)[i] = o;
}

// all 4 layers' W^T in one launch: blocks [0,128)=L0, [128,256)=L1,
// [256,384)=L2, [384,448)=L3 (O=64). WT[o][k], k<1024 -> W[k>>7][k&127][o],
// else root[k-1024][o].
__global__ void k_wtall(const float* __restrict__ W0, const float* __restrict__ R0,
                        const float* __restrict__ W1, const float* __restrict__ R1,
                        const float* __restrict__ W2, const float* __restrict__ R2,
                        const float* __restrict__ W3, const float* __restrict__ R3,
                        ushort* __restrict__ WT) {
    int b = blockIdx.x;
    int layer = (b < 384) ? (b >> 7) : 3;
    int o = (b < 384) ? (b & 127) : (b - 384);
    int O = (layer == 3) ? 64 : 128;
    const float* W  = (layer == 0) ? W0 : (layer == 1) ? W1 : (layer == 2) ? W2 : W3;
    const float* Rt = (layer == 0) ? R0 : (layer == 1) ? R1 : (layer == 2) ? R2 : R3;
    ushort* dst = WT + (size_t)layer * 147456;
    for (int k = threadIdx.x; k < KTOT; k += 256) {
        float v = (k < K1)
            ? W[(size_t)(k >> 7) * 128 * O + (size_t)(k & 127) * O + o]
            : Rt[(size_t)(k - K1) * O + o];
        dst[(size_t)o * KTOT + k] = (ushort)f2bf(v);
    }
}

// ---------------- edge preprocessing (counting sort by s = dst*8 + r) ----------------
__global__ void k_hist(const int* __restrict__ ei, const int* __restrict__ et,
                       int* __restrict__ hist) {
    int e = blockIdx.x * blockDim.x + threadIdx.x;
    if (e >= EE) return;
    atomicAdd(&hist[ei[EE + e] * RR + et[e]], 1);
}

__global__ void k_scan1(const int* __restrict__ hist, int* __restrict__ offs,
                        int* __restrict__ bsums) {
    __shared__ int tmp[1024];
    int tid = threadIdx.x;
    int g = blockIdx.x * 1024 + tid;
    int v = (g < RN) ? hist[g] : 0;
    tmp[tid] = v;
    __syncthreads();
    for (int off = 1; off < 1024; off <<= 1) {
        int t = tmp[tid];
        if (tid >= off) t += tmp[tid - off];
        __syncthreads();
        tmp[tid] = t;
        __syncthreads();
    }
    if (g < RN) offs[g] = tmp[tid] - v;
    if (tid == 1023) bsums[blockIdx.x] = tmp[1023];
}

__global__ void k_scan2(int* __restrict__ bsums) {
    __shared__ int tmp[1024];
    int tid = threadIdx.x;
    int v = (tid < NBLK) ? bsums[tid] : 0;
    tmp[tid] = v;
    __syncthreads();
    for (int off = 1; off < 1024; off <<= 1) {
        int t = tmp[tid];
        if (tid >= off) t += tmp[tid - off];
        __syncthreads();
        tmp[tid] = t;
        __syncthreads();
    }
    if (tid < NBLK) bsums[tid] = tmp[tid] - v;
}

__global__ void k_scan3(int* __restrict__ offs, const int* __restrict__ bsums) {
    int g = blockIdx.x * 1024 + threadIdx.x;
    if (g < RN) offs[g] += bsums[blockIdx.x];
    else if (g == RN) offs[RN] = EE;
}

__global__ void k_scatter(const int* __restrict__ ei, const int* __restrict__ et,
                          const int* __restrict__ offs, int* __restrict__ cur,
                          int* __restrict__ ssrc) {
    int e = blockIdx.x * blockDim.x + threadIdx.x;
    if (e >= EE) return;
    int s = ei[EE + e] * RR + et[e];
    ssrc[offs[s] + atomicAdd(&cur[s], 1)] = ei[e];
}

// ---------------- fused layer: agg -> LDS -> MFMA, K-split halves ----------------
// R19 = R16 champion inner loop, K-SPLIT into two halves to shrink LDS:
// half 0 = relations 0-3 (512 cols), half 1 = relations 4-7 + root (640 cols).
// As: 32 x 648 = 41.5 KB -> 3 blocks/CU = 24 waves/CU (was 2/16 at 74 KB).
// Mechanism: gather is concurrency-bound (R13: FETCH invariant; R18: src
// machinery off critical path; Little's law ~6 reqs in flight/CU) -> +50%
// resident waves at UNCHANGED inner code shape (VGPR preserved; the R12/R14
// collapse came from changing the loop shape, avoided here). acc persists
// across halves. SMAX: layer 4 fuses log-softmax via LDS f32 tile.
template<int O, bool RELU, bool SMAX>
__global__ __launch_bounds__(512) void k_fused(
        const ushort* __restrict__ hb, const int* __restrict__ offs,
        const int* __restrict__ ssrc, const ushort* __restrict__ WT,
        const float* __restrict__ bias, void* __restrict__ outv) {
    __shared__ ushort As[32 * LDWH];         // 41,472 B
    const int tid = threadIdx.x;
    const int lane = tid & 63;
    const int w = tid >> 6;                  // 0..7
    const int q = lane >> 4;                 // quarter 0..3 = relation slot
    const int ll = lane & 15;                // 16B chunk within row
    const int nbase = blockIdx.x * 32;
    const uint4* h16 = (const uint4*)hb;     // h row = 16 uint4

    constexpr int NTILE = O / 16;
    const int cw = w % NTILE;
    const int mt0 = (NTILE == 8) ? 0 : (w / NTILE);
    constexpr int NMT = (NTILE == 8) ? 2 : 1;
    const int lr = lane & 15, hi = lane >> 4;
    f32x4 acc[NMT] = {};                     // persists across halves

    for (int half = 0; half < 2; ++half) {
        const int rbase = half * 4;
        // ---- gather phase for this half: 2 node-pairs per wave
        for (int i = 0; i < 2; ++i) {        // wave-uniform
            int nlA = w * 4 + i * 2;
            int nlB = nlA + 1;
            int nA = min(nbase + nlA, NN - 1);
            int nB = min(nbase + nlB, NN - 1);
            // lanes 0-4: A's bounds rbase..rbase+4; lanes 32-36: B's
            int b = offs[((lane < 32) ? nA : nB) * 8 + rbase + min(lane & 31, 4)];
            int b0A = __shfl(b, 0),  b4A = __shfl(b, 4);
            int b0B = __shfl(b, 32), b4B = __shfl(b, 36);
            int nbA = b4A - b0A, nbB = b4B - b0B;   // half-degree (mean ~8)
            int svA = ssrc[min(b0A + min(lane, max(nbA - 1, 0)), EE - 1)];
            int svB = ssrc[min(b0B + min(lane, max(nbB - 1, 0)), EE - 1)];
            // quarter q handles relation rbase+q (one pass per half)
            int begA = __shfl(b, q),      endA = __shfl(b, q + 1);
            int begB = __shfl(b, 32 + q), endB = __shfl(b, 32 + q + 1);
            int lenA = endA - begA, lenB = endB - begB;
            int mxA = max(max(__shfl(lenA, 0), __shfl(lenA, 16)),
                          max(__shfl(lenA, 32), __shfl(lenA, 48)));
            int mxB = max(max(__shfl(lenB, 0), __shfl(lenB, 16)),
                          max(__shfl(lenB, 32), __shfl(lenB, 48)));
            int mx = max(mxA, mxB);          // wave-uniform trip count
            int beglA = begA - b0A, beglB = begB - b0B;
            float aA0 = 0.f, aA1 = 0.f, aA2 = 0.f, aA3 = 0.f;
            float aA4 = 0.f, aA5 = 0.f, aA6 = 0.f, aA7 = 0.f;
            float aB0 = 0.f, aB1 = 0.f, aB2 = 0.f, aB3 = 0.f;
            float aB4 = 0.f, aB5 = 0.f, aB6 = 0.f, aB7 = 0.f;
            for (int j = 0; j < mx; j += 4) {   // uniform trip: full exec
                int eA = beglA + j, eB = beglB + j;
                int sA0 = __shfl(svA, min(eA, 63));   // shfl ALWAYS full exec
                int sA1 = __shfl(svA, min(eA + 1, 63));
                int sA2 = __shfl(svA, min(eA + 2, 63));
                int sA3 = __shfl(svA, min(eA + 3, 63));
                int sB0 = __shfl(svB, min(eB, 63));
                int sB1 = __shfl(svB, min(eB + 1, 63));
                int sB2 = __shfl(svB, min(eB + 2, 63));
                int sB3 = __shfl(svB, min(eB + 3, 63));
                if (eA + 3 >= 64) {              // rare: half-degree > 64
                    sA0 = ssrc[min(b0A + eA, EE - 1)];
                    sA1 = ssrc[min(b0A + eA + 1, EE - 1)];
                    sA2 = ssrc[min(b0A + eA + 2, EE - 1)];
                    sA3 = ssrc[min(b0A + eA + 3, EE - 1)];
                }
                if (eB + 3 >= 64) {
                    sB0 = ssrc[min(b0B + eB, EE - 1)];
                    sB1 = ssrc[min(b0B + eB + 1, EE - 1)];
                    sB2 = ssrc[min(b0B + eB + 2, EE - 1)];
                    sB3 = ssrc[min(b0B + eB + 3, EE - 1)];
                }
                uint4 uA0 = h16[(size_t)sA0 * 16 + ll];   // 8 loads in flight,
                uint4 uA1 = h16[(size_t)sA1 * 16 + ll];   // unconditional (R13)
                uint4 uA2 = h16[(size_t)sA2 * 16 + ll];
                uint4 uA3 = h16[(size_t)sA3 * 16 + ll];
                uint4 uB0 = h16[(size_t)sB0 * 16 + ll];
                uint4 uB1 = h16[(size_t)sB1 * 16 + ll];
                uint4 uB2 = h16[(size_t)sB2 * 16 + ll];
                uint4 uB3 = h16[(size_t)sB3 * 16 + ll];
                if (j < lenA) {
                    aA0 += bflo(uA0.x); aA1 += bfhi(uA0.x);
                    aA2 += bflo(uA0.y); aA3 += bfhi(uA0.y);
                    aA4 += bflo(uA0.z); aA5 += bfhi(uA0.z);
                    aA6 += bflo(uA0.w); aA7 += bfhi(uA0.w);
                }
                if (j + 1 < lenA) {
                    aA0 += bflo(uA1.x); aA1 += bfhi(uA1.x);
                    aA2 += bflo(uA1.y); aA3 += bfhi(uA1.y);
                    aA4 += bflo(uA1.z); aA5 += bfhi(uA1.z);
                    aA6 += bflo(uA1.w); aA7 += bfhi(uA1.w);
                }
                if (j + 2 < lenA) {
                    aA0 += bflo(uA2.x); aA1 += bfhi(uA2.x);
                    aA2 += bflo(uA2.y); aA3 += bfhi(uA2.y);
                    aA4 += bflo(uA2.z); aA5 += bfhi(uA2.z);
                    aA6 += bflo(uA2.w); aA7 += bfhi(uA2.w);
                }
                if (j + 3 < lenA) {
                    aA0 += bflo(uA3.x); aA1 += bfhi(uA3.x);
                    aA2 += bflo(uA3.y); aA3 += bfhi(uA3.y);
                    aA4 += bflo(uA3.z); aA5 += bfhi(uA3.z);
                    aA6 += bflo(uA3.w); aA7 += bfhi(uA3.w);
                }
                if (j < lenB) {
                    aB0 += bflo(uB0.x); aB1 += bfhi(uB0.x);
                    aB2 += bflo(uB0.y); aB3 += bfhi(uB0.y);
                    aB4 += bflo(uB0.z); aB5 += bfhi(uB0.z);
                    aB6 += bflo(uB0.w); aB7 += bfhi(uB0.w);
                }
                if (j + 1 < lenB) {
                    aB0 += bflo(uB1.x); aB1 += bfhi(uB1.x);
                    aB2 += bflo(uB1.y); aB3 += bfhi(uB1.y);
                    aB4 += bflo(uB1.z); aB5 += bfhi(uB1.z);
                    aB6 += bflo(uB1.w); aB7 += bfhi(uB1.w);
                }
                if (j + 2 < lenB) {
                    aB0 += bflo(uB2.x); aB1 += bfhi(uB2.x);
                    aB2 += bflo(uB2.y); aB3 += bfhi(uB2.y);
                    aB4 += bflo(uB2.z); aB5 += bfhi(uB2.z);
                    aB6 += bflo(uB2.w); aB7 += bfhi(uB2.w);
                }
                if (j + 3 < lenB) {
                    aB0 += bflo(uB3.x); aB1 += bfhi(uB3.x);
                    aB2 += bflo(uB3.y); aB3 += bfhi(uB3.y);
                    aB4 += bflo(uB3.z); aB5 += bfhi(uB3.z);
                    aB6 += bflo(uB3.w); aB7 += bfhi(uB3.w);
                }
            }
            float invA = 1.0f / (float)max(lenA, 1);
            float invB = 1.0f / (float)max(lenB, 1);
            uint4 oA, oB;
            oA.x = f2bf(aA0 * invA) | (f2bf(aA1 * invA) << 16);
            oA.y = f2bf(aA2 * invA) | (f2bf(aA3 * invA) << 16);
            oA.z = f2bf(aA4 * invA) | (f2bf(aA5 * invA) << 16);
            oA.w = f2bf(aA6 * invA) | (f2bf(aA7 * invA) << 16);
            oB.x = f2bf(aB0 * invB) | (f2bf(aB1 * invB) << 16);
            oB.y = f2bf(aB2 * invB) | (f2bf(aB3 * invB) << 16);
            oB.z = f2bf(aB4 * invB) | (f2bf(aB5 * invB) << 16);
            oB.w = f2bf(aB6 * invB) | (f2bf(aB7 * invB) << 16);
            // local chunk = q*16 + ll (relation slot within this half)
            *(uint4*)(&As[nlA * LDWH + (q * 16 + ll) * 8]) = oA;
            *(uint4*)(&As[nlB * LDWH + (q * 16 + ll) * 8]) = oB;
        }
        // half 1 additionally stages root rows at local chunks [64,80)
        if (half == 1) {
            int row = tid >> 4;              // 0..31
            int cc = tid & 15;
            uint4 v = h16[(size_t)min(nbase + row, NN - 1) * 16 + cc];
            *(uint4*)(&As[row * LDWH + (64 + cc) * 8]) = v;
        }
        __syncthreads();
        // ---- MFMA phase for this half (16 or 20 K-steps)
        const int KS = (half == 0) ? 16 : 20;
        const ushort* wcol = WT + (size_t)(cw * 16 + lr) * KTOT
                                + half * 512 + hi * 8;
        for (int ks = 0; ks < KS; ++ks) {
            bf16x8 bb = *(const bf16x8*)(wcol + ks * 32);
            int g = ks * 4 + hi;
#pragma unroll
            for (int m = 0; m < NMT; ++m) {
                int row = (mt0 + m) * 16 + lr;
                bf16x8 a = *(const bf16x8*)(&As[row * LDWH + g * 8]);
                acc[m] = __builtin_amdgcn_mfma_f32_16x16x32_bf16(a, bb, acc[m], 0, 0, 0);
            }
        }
        __syncthreads();                     // WAR: next half (or SMAX) reuses As
    }
    // ---- epilogue
    int col = cw * 16 + lr;
    float bs = bias[col];
    if (!SMAX) {
#pragma unroll
        for (int m = 0; m < NMT; ++m) {
#pragma unroll
            for (int j = 0; j < 4; ++j) {    // C/D: col=lane&15, row=(lane>>4)*4+j
                int row = nbase + (mt0 + m) * 16 + hi * 4 + j;
                if (row >= NN) continue;
                float v = acc[m][j] + bs;
                if (RELU) v = fmaxf(v, 0.f);
                ((ushort*)outv)[(size_t)row * O + col] = (ushort)f2bf(v);
            }
        }
    } else {
        // fused log-softmax (O=64, NMT=1): stage rows in LDS f32 tile [32][65]
        float* Asf = (float*)As;
#pragma unroll
        for (int j = 0; j < 4; ++j) {
            int rl = mt0 * 16 + hi * 4 + j;  // local row 0..31
            Asf[rl * 65 + col] = acc[0][j] + bs;
        }
        __syncthreads();
        // wave w reduces rows 4w..4w+3 (64 lanes = 64 cols)
        for (int rr = 0; rr < 4; ++rr) {
            int rl = w * 4 + rr;
            float v = Asf[rl * 65 + lane];
            float m = v;
#pragma unroll
            for (int off = 32; off; off >>= 1) m = fmaxf(m, __shfl_xor(m, off, 64));
            float e = expf(v - m);
            float s = e;
#pragma unroll
            for (int off = 32; off; off >>= 1) s += __shfl_xor(s, off, 64);
            int row = nbase + rl;
            if (row < NN)
                ((float*)outv)[(size_t)row * 64 + lane] = v - m - logf(s);
        }
    }
}

extern "C" void kernel_launch(void* const* d_in, const int* in_sizes, int n_in,
                              void* d_out, int out_size, void* d_ws, size_t ws_size,
                              hipStream_t stream) {
    const float* x  = (const float*)d_in[0];
    const int*   ei = (const int*)d_in[1];
    const int*   et = (const int*)d_in[2];
    const float* W[4]    = {(const float*)d_in[3], (const float*)d_in[6],
                            (const float*)d_in[9], (const float*)d_in[12]};
    const float* root[4] = {(const float*)d_in[4], (const float*)d_in[7],
                            (const float*)d_in[10], (const float*)d_in[13]};
    const float* bias[4] = {(const float*)d_in[5], (const float*)d_in[8],
                            (const float*)d_in[11], (const float*)d_in[14]};

    if (ws_size < WS_NEED) return;

    char* ws = (char*)d_ws;
    ushort* hb0  = (ushort*)(ws + OFF_HB0);
    ushort* hb1  = (ushort*)(ws + OFF_HB1);
    ushort* xb   = (ushort*)(ws + OFF_XB);
    ushort* WT   = (ushort*)(ws + OFF_WT);
    int*   offs  = (int*)(ws + OFF_OFFS);
    int*   cur   = (int*)(ws + OFF_CUR);
    int*   ssrc  = (int*)(ws + OFF_SRT);
    int*   bsums = (int*)(ws + OFF_BS);
    ushort* WTl[4] = {WT, WT + 147456, WT + 2 * 147456, WT + 3 * 147456};

    // one-time converts (2 launches)
    k_cvt<<<(NN * 32 + 255) / 256, 256, 0, stream>>>(x, xb);
    k_wtall<<<448, 256, 0, stream>>>(W[0], root[0], W[1], root[1],
                                     W[2], root[2], W[3], root[3], WT);

    // edge sort by segment key s = dst*8 + etype
    hipMemsetAsync(cur, 0, RN * sizeof(int), stream);
    k_hist<<<(EE + 255) / 256, 256, 0, stream>>>(ei, et, cur);
    k_scan1<<<NBLK, 1024, 0, stream>>>(cur, offs, bsums);
    k_scan2<<<1, 1024, 0, stream>>>(bsums);
    k_scan3<<<NBLK + 1, 1024, 0, stream>>>(offs, bsums);
    hipMemsetAsync(cur, 0, RN * sizeof(int), stream);
    k_scatter<<<(EE + 255) / 256, 256, 0, stream>>>(ei, et, offs, cur, ssrc);

    const int G = (NN + 31) / 32;   // 1563
    k_fused<128, true,  false><<<G, 512, 0, stream>>>(xb,  offs, ssrc, WTl[0], bias[0], hb0);
    k_fused<128, true,  false><<<G, 512, 0, stream>>>(hb0, offs, ssrc, WTl[1], bias[1], hb1);
    k_fused<128, true,  false><<<G, 512, 0, stream>>>(hb1, offs, ssrc, WTl[2], bias[2], hb0);
    k_fused<64,  false, true ><<<G, 512, 0, stream>>>(hb0, offs, ssrc, WTl[3], bias[3], d_out);
}

// Round 20
// 507.603 us; speedup vs baseline: 1.0558x; 1.0162x over previous
//
#include <hip/hip_runtime.h>
#include <math.h>

#define NN 50000
#define RR 8
#define EE 800000
#define RN 400000            // RR * NN
#define DIN 128
#define K1 1024              // RR * DIN
#define KTOT 1152            // K1 + DIN
#define NBLK 391             // ceil(RN / 1024)
#define LDW 1160             // LDS row width (elems) = 145 16B-chunks (ODD -> natural
                             // per-row bank rotation; NO XOR swizzle — R10 post-mortem)

// ---------------- workspace layout (bytes) ----------------
#define OFF_HB0  0UL           // h bf16: [NN][128] = 12,800,000
#define OFF_HB1  12800000UL    // h bf16: [NN][128] = 12,800,000
#define OFF_XB   25600000UL    // x bf16: [NN][128] = 12,800,000
#define OFF_WT   51200000UL    // W^T bf16: 4 x 147456 elems = 1,179,648
#define OFF_OFFS 52379648UL    // offsets: (RN+1) ints -> 1,600,128
#define OFF_CUR  53979776UL    // cursor/hist: RN ints = 1,600,000
#define OFF_SRT  55579776UL    // sorted_src: EE ints = 3,200,000
#define OFF_BS   58779776UL    // block sums = 4,096
#define WS_NEED  58783872UL

typedef short bf16x8 __attribute__((ext_vector_type(8)));
typedef float f32x4 __attribute__((ext_vector_type(4)));

__device__ __forceinline__ unsigned f2bf(float f) {       // RNE f32 -> bf16 bits
    unsigned x = __float_as_uint(f);
    return (x + 0x7fffu + ((x >> 16) & 1u)) >> 16;
}
__device__ __forceinline__ float bflo(unsigned p) { return __uint_as_float(p << 16); }
__device__ __forceinline__ float bfhi(unsigned p) { return __uint_as_float(p & 0xffff0000u); }

// ---------------- one-time converts ----------------
__global__ void k_cvt(const float* __restrict__ x, ushort* __restrict__ xb) {
    int i = blockIdx.x * 256 + threadIdx.x;
    if (i >= NN * 32) return;                 // float4 granules
    float4 v = ((const float4*)x)[i];
    ushort4 o;
    o.x = (ushort)f2bf(v.x); o.y = (ushort)f2bf(v.y);
    o.z = (ushort)f2bf(v.z); o.w = (ushort)f2bf(v.w);
    ((ushort4*)xb)[i] = o;
}

// all 4 layers' W^T in one launch: blocks [0,128)=L0, [128,256)=L1,
// [256,384)=L2, [384,448)=L3 (O=64). WT[o][k], k<1024 -> W[k>>7][k&127][o],
// else root[k-1024][o].
__global__ void k_wtall(const float* __restrict__ W0, const float* __restrict__ R0,
                        const float* __restrict__ W1, const float* __restrict__ R1,
                        const float* __restrict__ W2, const float* __restrict__ R2,
                        const float* __restrict__ W3, const float* __restrict__ R3,
                        ushort* __restrict__ WT) {
    int b = blockIdx.x;
    int layer = (b < 384) ? (b >> 7) : 3;
    int o = (b < 384) ? (b & 127) : (b - 384);
    int O = (layer == 3) ? 64 : 128;
    const float* W  = (layer == 0) ? W0 : (layer == 1) ? W1 : (layer == 2) ? W2 : W3;
    const float* Rt = (layer == 0) ? R0 : (layer == 1) ? R1 : (layer == 2) ? R2 : R3;
    ushort* dst = WT + (size_t)layer * 147456;
    for (int k = threadIdx.x; k < KTOT; k += 256) {
        float v = (k < K1)
            ? W[(size_t)(k >> 7) * 128 * O + (size_t)(k & 127) * O + o]
            : Rt[(size_t)(k - K1) * O + o];
        dst[(size_t)o * KTOT + k] = (ushort)f2bf(v);
    }
}

// ---------------- edge preprocessing (counting sort by s = dst*8 + r) ----------------
__global__ void k_hist(const int* __restrict__ ei, const int* __restrict__ et,
                       int* __restrict__ hist) {
    int e = blockIdx.x * blockDim.x + threadIdx.x;
    if (e >= EE) return;
    atomicAdd(&hist[ei[EE + e] * RR + et[e]], 1);
}

__global__ void k_scan1(const int* __restrict__ hist, int* __restrict__ offs,
                        int* __restrict__ bsums) {
    __shared__ int tmp[1024];
    int tid = threadIdx.x;
    int g = blockIdx.x * 1024 + tid;
    int v = (g < RN) ? hist[g] : 0;
    tmp[tid] = v;
    __syncthreads();
    for (int off = 1; off < 1024; off <<= 1) {
        int t = tmp[tid];
        if (tid >= off) t += tmp[tid - off];
        __syncthreads();
        tmp[tid] = t;
        __syncthreads();
    }
    if (g < RN) offs[g] = tmp[tid] - v;
    if (tid == 1023) bsums[blockIdx.x] = tmp[1023];
}

__global__ void k_scan2(int* __restrict__ bsums) {
    __shared__ int tmp[1024];
    int tid = threadIdx.x;
    int v = (tid < NBLK) ? bsums[tid] : 0;
    tmp[tid] = v;
    __syncthreads();
    for (int off = 1; off < 1024; off <<= 1) {
        int t = tmp[tid];
        if (tid >= off) t += tmp[tid - off];
        __syncthreads();
        tmp[tid] = t;
        __syncthreads();
    }
    if (tid < NBLK) bsums[tid] = tmp[tid] - v;
}

__global__ void k_scan3(int* __restrict__ offs, const int* __restrict__ bsums) {
    int g = blockIdx.x * 1024 + threadIdx.x;
    if (g < RN) offs[g] += bsums[blockIdx.x];
    else if (g == RN) offs[RN] = EE;
}

__global__ void k_scatter(const int* __restrict__ ei, const int* __restrict__ et,
                          const int* __restrict__ offs, int* __restrict__ cur,
                          int* __restrict__ ssrc) {
    int e = blockIdx.x * blockDim.x + threadIdx.x;
    if (e >= EE) return;
    int s = ei[EE + e] * RR + et[e];
    ssrc[offs[s] + atomicAdd(&cur[s], 1)] = ei[e];
}

// ---------------- fused layer: agg -> LDS -> MFMA, one barrier ----------------
// R20 = best-of-each recomposition: R16's champion full-K gather (107us: 32-node
// block, 512 thr, A/B chain interleave, 4-deep unroll, VGPR 52) + R19's fused
// log-softmax epilogue (SMAX path, O=64 only — L1-3 codegen untouched) + k_wtall.
// R19's K-split reverted (cost +5us/layer, occupancy never moved — gather is
// capped by per-CU outstanding-request latency product, not resident waves).
template<int O, bool RELU, bool SMAX>
__global__ __launch_bounds__(512) void k_fused(
        const ushort* __restrict__ hb, const int* __restrict__ offs,
        const int* __restrict__ ssrc, const ushort* __restrict__ WT,
        const float* __restrict__ bias, void* __restrict__ outv) {
    __shared__ ushort As[32 * LDW];
    const int tid = threadIdx.x;
    const int lane = tid & 63;
    const int w = tid >> 6;                  // 0..7
    const int q = lane >> 4;                 // quarter 0..3 = relation slot
    const int ll = lane & 15;                // 16B chunk within row
    const int nbase = blockIdx.x * 32;
    const uint4* h16 = (const uint4*)hb;     // h row = 16 uint4

    // ---- phase 1: 2 node-pairs per wave, A/B chains interleaved
    for (int i = 0; i < 2; ++i) {            // wave-uniform
        int nlA = w * 4 + i * 2;
        int nlB = nlA + 1;
        int nA = min(nbase + nlA, NN - 1);   // clamp tail (junk masked later)
        int nB = min(nbase + nlB, NN - 1);
        // one offs load: lanes 0-31 node A bounds, lanes 32-63 node B bounds
        int b = offs[((lane < 32) ? nA : nB) * 8 + min(lane & 31, 8)];
        int b0A = __shfl(b, 0),  b8A = __shfl(b, 8);
        int b0B = __shfl(b, 32), b8B = __shfl(b, 40);
        int nbA = b8A - b0A, nbB = b8B - b0B;
        int svA = ssrc[min(b0A + min(lane, max(nbA - 1, 0)), EE - 1)];
        int svB = ssrc[min(b0B + min(lane, max(nbB - 1, 0)), EE - 1)];
#pragma unroll
        for (int p = 0; p < 2; ++p) {        // relation pass: r = p*4 + q
            int r = p * 4 + q;
            int begA = __shfl(b, r),      endA = __shfl(b, r + 1);
            int begB = __shfl(b, 32 + r), endB = __shfl(b, 32 + r + 1);
            int lenA = endA - begA, lenB = endB - begB;
            int mxA = max(max(__shfl(lenA, 0), __shfl(lenA, 16)),
                          max(__shfl(lenA, 32), __shfl(lenA, 48)));
            int mxB = max(max(__shfl(lenB, 0), __shfl(lenB, 16)),
                          max(__shfl(lenB, 32), __shfl(lenB, 48)));
            int mx = max(mxA, mxB);          // wave-uniform trip count
            int beglA = begA - b0A, beglB = begB - b0B;
            float aA0 = 0.f, aA1 = 0.f, aA2 = 0.f, aA3 = 0.f;
            float aA4 = 0.f, aA5 = 0.f, aA6 = 0.f, aA7 = 0.f;
            float aB0 = 0.f, aB1 = 0.f, aB2 = 0.f, aB3 = 0.f;
            float aB4 = 0.f, aB5 = 0.f, aB6 = 0.f, aB7 = 0.f;
            for (int j = 0; j < mx; j += 4) {   // uniform trip: full exec
                int eA = beglA + j, eB = beglB + j;
                int sA0 = __shfl(svA, min(eA, 63));       // shfl ALWAYS full exec
                int sA1 = __shfl(svA, min(eA + 1, 63));
                int sA2 = __shfl(svA, min(eA + 2, 63));
                int sA3 = __shfl(svA, min(eA + 3, 63));
                int sB0 = __shfl(svB, min(eB, 63));
                int sB1 = __shfl(svB, min(eB + 1, 63));
                int sB2 = __shfl(svB, min(eB + 2, 63));
                int sB3 = __shfl(svB, min(eB + 3, 63));
                if (eA + 3 >= 64) {              // rare: degree > 64
                    sA0 = ssrc[min(b0A + eA, EE - 1)];
                    sA1 = ssrc[min(b0A + eA + 1, EE - 1)];
                    sA2 = ssrc[min(b0A + eA + 2, EE - 1)];
                    sA3 = ssrc[min(b0A + eA + 3, EE - 1)];
                }
                if (eB + 3 >= 64) {
                    sB0 = ssrc[min(b0B + eB, EE - 1)];
                    sB1 = ssrc[min(b0B + eB + 1, EE - 1)];
                    sB2 = ssrc[min(b0B + eB + 2, EE - 1)];
                    sB3 = ssrc[min(b0B + eB + 3, EE - 1)];
                }
                uint4 uA0 = h16[(size_t)sA0 * 16 + ll];   // 8 loads in flight
                uint4 uA1 = h16[(size_t)sA1 * 16 + ll];
                uint4 uA2 = h16[(size_t)sA2 * 16 + ll];
                uint4 uA3 = h16[(size_t)sA3 * 16 + ll];
                uint4 uB0 = h16[(size_t)sB0 * 16 + ll];
                uint4 uB1 = h16[(size_t)sB1 * 16 + ll];
                uint4 uB2 = h16[(size_t)sB2 * 16 + ll];
                uint4 uB3 = h16[(size_t)sB3 * 16 + ll];
                if (j < lenA) {
                    aA0 += bflo(uA0.x); aA1 += bfhi(uA0.x);
                    aA2 += bflo(uA0.y); aA3 += bfhi(uA0.y);
                    aA4 += bflo(uA0.z); aA5 += bfhi(uA0.z);
                    aA6 += bflo(uA0.w); aA7 += bfhi(uA0.w);
                }
                if (j + 1 < lenA) {
                    aA0 += bflo(uA1.x); aA1 += bfhi(uA1.x);
                    aA2 += bflo(uA1.y); aA3 += bfhi(uA1.y);
                    aA4 += bflo(uA1.z); aA5 += bfhi(uA1.z);
                    aA6 += bflo(uA1.w); aA7 += bfhi(uA1.w);
                }
                if (j + 2 < lenA) {
                    aA0 += bflo(uA2.x); aA1 += bfhi(uA2.x);
                    aA2 += bflo(uA2.y); aA3 += bfhi(uA2.y);
                    aA4 += bflo(uA2.z); aA5 += bfhi(uA2.z);
                    aA6 += bflo(uA2.w); aA7 += bfhi(uA2.w);
                }
                if (j + 3 < lenA) {
                    aA0 += bflo(uA3.x); aA1 += bfhi(uA3.x);
                    aA2 += bflo(uA3.y); aA3 += bfhi(uA3.y);
                    aA4 += bflo(uA3.z); aA5 += bfhi(uA3.z);
                    aA6 += bflo(uA3.w); aA7 += bfhi(uA3.w);
                }
                if (j < lenB) {
                    aB0 += bflo(uB0.x); aB1 += bfhi(uB0.x);
                    aB2 += bflo(uB0.y); aB3 += bfhi(uB0.y);
                    aB4 += bflo(uB0.z); aB5 += bfhi(uB0.z);
                    aB6 += bflo(uB0.w); aB7 += bfhi(uB0.w);
                }
                if (j + 1 < lenB) {
                    aB0 += bflo(uB1.x); aB1 += bfhi(uB1.x);
                    aB2 += bflo(uB1.y); aB3 += bfhi(uB1.y);
                    aB4 += bflo(uB1.z); aB5 += bfhi(uB1.z);
                    aB6 += bflo(uB1.w); aB7 += bfhi(uB1.w);
                }
                if (j + 2 < lenB) {
                    aB0 += bflo(uB2.x); aB1 += bfhi(uB2.x);
                    aB2 += bflo(uB2.y); aB3 += bfhi(uB2.y);
                    aB4 += bflo(uB2.z); aB5 += bfhi(uB2.z);
                    aB6 += bflo(uB2.w); aB7 += bfhi(uB2.w);
                }
                if (j + 3 < lenB) {
                    aB0 += bflo(uB3.x); aB1 += bfhi(uB3.x);
                    aB2 += bflo(uB3.y); aB3 += bfhi(uB3.y);
                    aB4 += bflo(uB3.z); aB5 += bfhi(uB3.z);
                    aB6 += bflo(uB3.w); aB7 += bfhi(uB3.w);
                }
            }
            float invA = 1.0f / (float)max(lenA, 1);
            float invB = 1.0f / (float)max(lenB, 1);
            uint4 oA, oB;
            oA.x = f2bf(aA0 * invA) | (f2bf(aA1 * invA) << 16);
            oA.y = f2bf(aA2 * invA) | (f2bf(aA3 * invA) << 16);
            oA.z = f2bf(aA4 * invA) | (f2bf(aA5 * invA) << 16);
            oA.w = f2bf(aA6 * invA) | (f2bf(aA7 * invA) << 16);
            oB.x = f2bf(aB0 * invB) | (f2bf(aB1 * invB) << 16);
            oB.y = f2bf(aB2 * invB) | (f2bf(aB3 * invB) << 16);
            oB.z = f2bf(aB4 * invB) | (f2bf(aB5 * invB) << 16);
            oB.w = f2bf(aB6 * invB) | (f2bf(aB7 * invB) << 16);
            *(uint4*)(&As[nlA * LDW + (r * 16 + ll) * 8]) = oA;
            *(uint4*)(&As[nlB * LDW + (r * 16 + ll) * 8]) = oB;
        }
    }
    // ---- root rows: cols [1024,1152) = chunks [128,144); 512 thr x 16B = 32 rows
    {
        int row = tid >> 4;                  // 0..31
        int cc = tid & 15;
        uint4 v = h16[(size_t)min(nbase + row, NN - 1) * 16 + cc];
        *(uint4*)(&As[row * LDW + (128 + cc) * 8]) = v;
    }
    __syncthreads();
    // ---- phase 2: MFMA. O=128 -> wave w: col-tile w, m-subtiles 0,1;
    //      O=64 -> wave w: col-tile w&3, m-subtile w>>2.
    constexpr int NTILE = O / 16;
    const int cw = w % NTILE;
    const int mt0 = (NTILE == 8) ? 0 : (w / NTILE);
    constexpr int NMT = (NTILE == 8) ? 2 : 1;
    const int lr = lane & 15, hi = lane >> 4;
    f32x4 acc[NMT] = {};
    const ushort* wcol = WT + (size_t)(cw * 16 + lr) * KTOT + hi * 8;
#pragma unroll
    for (int ks = 0; ks < 36; ++ks) {
        bf16x8 bb = *(const bf16x8*)(wcol + ks * 32);
        int g = ks * 4 + hi;
#pragma unroll
        for (int m = 0; m < NMT; ++m) {
            int row = (mt0 + m) * 16 + lr;
            bf16x8 a = *(const bf16x8*)(&As[row * LDW + g * 8]);
            acc[m] = __builtin_amdgcn_mfma_f32_16x16x32_bf16(a, bb, acc[m], 0, 0, 0);
        }
    }
    int col = cw * 16 + lr;
    float bs = bias[col];
    if (!SMAX) {
#pragma unroll
        for (int m = 0; m < NMT; ++m) {
#pragma unroll
            for (int j = 0; j < 4; ++j) {    // C/D: col=lane&15, row=(lane>>4)*4+j
                int row = nbase + (mt0 + m) * 16 + hi * 4 + j;
                if (row >= NN) continue;
                float v = acc[m][j] + bs;
                if (RELU) v = fmaxf(v, 0.f);
                ((ushort*)outv)[(size_t)row * O + col] = (ushort)f2bf(v);
            }
        }
    } else {
        // fused log-softmax (O=64, NMT=1): stage rows in LDS f32 tile [32][65]
        __syncthreads();                     // done reading As as bf16
        float* Asf = (float*)As;
#pragma unroll
        for (int j = 0; j < 4; ++j) {
            int rl = mt0 * 16 + hi * 4 + j;  // local row 0..31
            Asf[rl * 65 + col] = acc[0][j] + bs;
        }
        __syncthreads();
        // wave w reduces rows 4w..4w+3 (64 lanes = 64 cols)
        for (int rr = 0; rr < 4; ++rr) {
            int rl = w * 4 + rr;
            float v = Asf[rl * 65 + lane];
            float m = v;
#pragma unroll
            for (int off = 32; off; off >>= 1) m = fmaxf(m, __shfl_xor(m, off, 64));
            float e = expf(v - m);
            float s = e;
#pragma unroll
            for (int off = 32; off; off >>= 1) s += __shfl_xor(s, off, 64);
            int row = nbase + rl;
            if (row < NN)
                ((float*)outv)[(size_t)row * 64 + lane] = v - m - logf(s);
        }
    }
}

extern "C" void kernel_launch(void* const* d_in, const int* in_sizes, int n_in,
                              void* d_out, int out_size, void* d_ws, size_t ws_size,
                              hipStream_t stream) {
    const float* x  = (const float*)d_in[0];
    const int*   ei = (const int*)d_in[1];
    const int*   et = (const int*)d_in[2];
    const float* W[4]    = {(const float*)d_in[3], (const float*)d_in[6],
                            (const float*)d_in[9], (const float*)d_in[12]};
    const float* root[4] = {(const float*)d_in[4], (const float*)d_in[7],
                            (const float*)d_in[10], (const float*)d_in[13]};
    const float* bias[4] = {(const float*)d_in[5], (const float*)d_in[8],
                            (const float*)d_in[11], (const float*)d_in[14]};

    if (ws_size < WS_NEED) return;

    char* ws = (char*)d_ws;
    ushort* hb0  = (ushort*)(ws + OFF_HB0);
    ushort* hb1  = (ushort*)(ws + OFF_HB1);
    ushort* xb   = (ushort*)(ws + OFF_XB);
    ushort* WT   = (ushort*)(ws + OFF_WT);
    int*   offs  = (int*)(ws + OFF_OFFS);
    int*   cur   = (int*)(ws + OFF_CUR);
    int*   ssrc  = (int*)(ws + OFF_SRT);
    int*   bsums = (int*)(ws + OFF_BS);
    ushort* WTl[4] = {WT, WT + 147456, WT + 2 * 147456, WT + 3 * 147456};

    // one-time converts (2 launches)
    k_cvt<<<(NN * 32 + 255) / 256, 256, 0, stream>>>(x, xb);
    k_wtall<<<448, 256, 0, stream>>>(W[0], root[0], W[1], root[1],
                                     W[2], root[2], W[3], root[3], WT);

    // edge sort by segment key s = dst*8 + etype
    hipMemsetAsync(cur, 0, RN * sizeof(int), stream);
    k_hist<<<(EE + 255) / 256, 256, 0, stream>>>(ei, et, cur);
    k_scan1<<<NBLK, 1024, 0, stream>>>(cur, offs, bsums);
    k_scan2<<<1, 1024, 0, stream>>>(bsums);
    k_scan3<<<NBLK + 1, 1024, 0, stream>>>(offs, bsums);
    hipMemsetAsync(cur, 0, RN * sizeof(int), stream);
    k_scatter<<<(EE + 255) / 256, 256, 0, stream>>>(ei, et, offs, cur, ssrc);

    const int G = (NN + 31) / 32;   // 1563
    k_fused<128, true,  false><<<G, 512, 0, stream>>>(xb,  offs, ssrc, WTl[0], bias[0], hb0);
    k_fused<128, true,  false><<<G, 512, 0, stream>>>(hb0, offs, ssrc, WTl[1], bias[1], hb1);
    k_fused<128, true,  false><<<G, 512, 0, stream>>>(hb1, offs, ssrc, WTl[2], bias[2], hb0);
    k_fused<64,  false, true ><<<G, 512, 0, stream>>>(hb0, offs, ssrc, WTl[3], bias[3], d_out);
}